// Round 9
// baseline (409.484 us; speedup 1.0000x reference)
//
#include <hip/hip_runtime.h>
#include <hip/hip_bf16.h>

#define N_NODES 100000
#define N_EDGES 1600000
#define D_IN 256
#define D_OUT 128
#define CAP 64            /* padded bucket capacity per row (max degree ~40) */

typedef short bf16x8 __attribute__((ext_vector_type(8)));
typedef float f32x4 __attribute__((ext_vector_type(4)));

__device__ __forceinline__ unsigned short f2bf(float f) {
    unsigned int u = __builtin_bit_cast(unsigned int, f);
    u += 0x7fffu + ((u >> 16) & 1u);   // round-to-nearest-even
    return (unsigned short)(u >> 16);
}
__device__ __forceinline__ float bf_lo(unsigned int h) {
    return __builtin_bit_cast(float, h << 16);
}
__device__ __forceinline__ float bf_hi(unsigned int h) {
    return __builtin_bit_cast(float, h & 0xffff0000u);
}

// ---------- W transpose+convert + cursor init ----------
// bucket_mode: cursor[i] = i*CAP (padded-CSR base); else cursor[i] = 0.
__global__ __launch_bounds__(256) void convert_w(const float* __restrict__ W,
                                                 unsigned short* __restrict__ WbT,
                                                 int* __restrict__ cursor,
                                                 int bucket_mode) {
    int i = blockIdx.x * 256 + threadIdx.x;      // 32768 total
    int k = i >> 7;
    int n = i & 127;
    WbT[(size_t)n * D_IN + k] = f2bf(W[i]);
    int z = i * 4;                                // init 100000 ints (int4 stores)
    if (z < N_NODES) {
        int4 v = bucket_mode ? make_int4(z << 6, (z << 6) + CAP, (z << 6) + 2 * CAP, (z << 6) + 3 * CAP)
                             : make_int4(0, 0, 0, 0);
        *(int4*)(cursor + z) = v;
    }
}

// ---------- GEMM: hb = bf16(x @ W), MFMA 16x16x32, 16 rows/wave ----------
#define GEMM_BLOCKS ((N_NODES + 63) / 64)            /* 1563 */
__global__ __launch_bounds__(256) void gemm_mfma(const float* __restrict__ x,
                                                 const unsigned short* __restrict__ WbT,
                                                 unsigned short* __restrict__ hb) {
    const int wave = threadIdx.x >> 6;
    const int lane = threadIdx.x & 63;
    const int row0 = blockIdx.x * 64 + wave * 16;
    if (row0 >= N_NODES) return;                 // wave-uniform (100000 % 16 == 0)
    const int m = lane & 15;
    const int q = lane >> 4;

    const float* xr = x + (size_t)(row0 + m) * D_IN + q * 8;

    float4 a[8][2];
#pragma unroll
    for (int kc = 0; kc < 8; ++kc) {
        a[kc][0] = *(const float4*)(xr + kc * 32);
        a[kc][1] = *(const float4*)(xr + kc * 32 + 4);
    }

    bf16x8 af[8];
#pragma unroll
    for (int kc = 0; kc < 8; ++kc) {
        af[kc][0] = (short)f2bf(a[kc][0].x); af[kc][1] = (short)f2bf(a[kc][0].y);
        af[kc][2] = (short)f2bf(a[kc][0].z); af[kc][3] = (short)f2bf(a[kc][0].w);
        af[kc][4] = (short)f2bf(a[kc][1].x); af[kc][5] = (short)f2bf(a[kc][1].y);
        af[kc][6] = (short)f2bf(a[kc][1].z); af[kc][7] = (short)f2bf(a[kc][1].w);
    }

    f32x4 acc[8];
#pragma unroll
    for (int nt = 0; nt < 8; ++nt) acc[nt] = (f32x4){0.f, 0.f, 0.f, 0.f};

#pragma unroll
    for (int kc = 0; kc < 8; ++kc) {
        const int kb = kc * 32 + q * 8;
#pragma unroll
        for (int nt = 0; nt < 8; ++nt) {
            bf16x8 bf = *(const bf16x8*)(WbT + (size_t)(nt * 16 + m) * D_IN + kb);
            acc[nt] = __builtin_amdgcn_mfma_f32_16x16x32_bf16(af[kc], bf, acc[nt], 0, 0, 0);
        }
    }

    // D layout: row = q*4 + r, col = nt*16 + m
#pragma unroll
    for (int nt = 0; nt < 8; ++nt)
#pragma unroll
        for (int r = 0; r < 4; ++r) {
            int grow = row0 + q * 4 + r;
            hb[(size_t)grow * D_OUT + nt * 16 + m] = f2bf(acc[nt][r]);
        }
}

// ---------- PRIMARY: windowed scatter of edge INDICES (4B) into padded buckets ----------
// v2: payload 8B->4B (edge index; gather dereferences cols/vals). Each XCD's
// destination window is now 12500*64*4 = 3.2MB < 4MiB L2, so 64B lines
// accumulate all 16 entries before one full-line writeback (round-8's 8B
// payload made the window 6.4MB > L2: WRITE_SIZE stayed 95MB). Scatter also
// no longer reads cols/vals at all — fetch is the pure rows stream.
#define NWIN 8
#define ROWS_PER_WIN (N_NODES / NWIN)   /* 12500 */
#define PERM_SLICES 250                 /* 2000 blocks; 400000/250 = 1600 int4 per slice */
__global__ __launch_bounds__(256) void scatter_bucket(const int* __restrict__ rows,
                                                      int* __restrict__ cursor,
                                                      int* __restrict__ buckets) {
    const int w     = blockIdx.x & (NWIN - 1);
    const int slice = blockIdx.x >> 3;
    const int lo = w * ROWS_PER_WIN;
    const int hi = lo + ROWS_PER_WIN;
    const int per = (N_EDGES / 4) / PERM_SLICES;  // 1600
    const int beg = slice * per;
    const int end = beg + per;
    for (int i = beg + (int)threadIdx.x; i < end; i += 256) {
        int4 r = *((const int4*)rows + i);
        const int e = i * 4;
        if (r.x >= lo && r.x < hi) {
            int p = atomicAdd(&cursor[r.x], 1);
            buckets[p] = e + 0;
        }
        if (r.y >= lo && r.y < hi) {
            int p = atomicAdd(&cursor[r.y], 1);
            buckets[p] = e + 1;
        }
        if (r.z >= lo && r.z < hi) {
            int p = atomicAdd(&cursor[r.z], 1);
            buckets[p] = e + 2;
        }
        if (r.w >= lo && r.w < hi) {
            int p = atomicAdd(&cursor[r.w], 1);
            buckets[p] = e + 3;
        }
    }
}

// ---------- PRIMARY gather: idx -> cols[idx], vals[idx], hb row ----------
// beg = row*CAP is 16B-aligned -> int4 loads of 4 indices at a time.
// cols/vals (6.4MB each) are L2/L3-resident; 4-edge ILP hides the extra
// dependent-load level.
__global__ __launch_bounds__(256) void gather_bucket(const int* __restrict__ cursor,
                                                     const int* __restrict__ buckets,
                                                     const int* __restrict__ cols,
                                                     const float* __restrict__ vals,
                                                     const unsigned short* __restrict__ hb,
                                                     float* __restrict__ out) {
    int row  = blockIdx.x * 4 + (threadIdx.x >> 6);
    int lane = threadIdx.x & 63;
    if (row >= N_NODES) return;
    int beg = row << 6;                                            // row*CAP
    int end = __builtin_amdgcn_readfirstlane(cursor[row]);

    float ax0 = 0.f, ay0 = 0.f, ax1 = 0.f, ay1 = 0.f;
    float ax2 = 0.f, ay2 = 0.f, ax3 = 0.f, ay3 = 0.f;
    int j = beg;
    for (; j + 4 <= end; j += 4) {
        int4 i4 = *(const int4*)(buckets + j);
        int c0 = cols[i4.x], c1 = cols[i4.y], c2 = cols[i4.z], c3 = cols[i4.w];
        float v0 = vals[i4.x], v1 = vals[i4.y], v2 = vals[i4.z], v3 = vals[i4.w];
        unsigned int h0 = *(const unsigned int*)(hb + (size_t)c0 * D_OUT + lane * 2);
        unsigned int h1 = *(const unsigned int*)(hb + (size_t)c1 * D_OUT + lane * 2);
        unsigned int h2 = *(const unsigned int*)(hb + (size_t)c2 * D_OUT + lane * 2);
        unsigned int h3 = *(const unsigned int*)(hb + (size_t)c3 * D_OUT + lane * 2);
        ax0 = fmaf(v0, bf_lo(h0), ax0); ay0 = fmaf(v0, bf_hi(h0), ay0);
        ax1 = fmaf(v1, bf_lo(h1), ax1); ay1 = fmaf(v1, bf_hi(h1), ay1);
        ax2 = fmaf(v2, bf_lo(h2), ax2); ay2 = fmaf(v2, bf_hi(h2), ay2);
        ax3 = fmaf(v3, bf_lo(h3), ax3); ay3 = fmaf(v3, bf_hi(h3), ay3);
    }
    for (; j < end; ++j) {
        int idx = buckets[j];
        int c = cols[idx];
        float v = vals[idx];
        unsigned int h = *(const unsigned int*)(hb + (size_t)c * D_OUT + lane * 2);
        ax0 = fmaf(v, bf_lo(h), ax0);
        ay0 = fmaf(v, bf_hi(h), ay0);
    }
    float accx = (ax0 + ax1) + (ax2 + ax3);
    float accy = (ay0 + ay1) + (ay2 + ay3);
    float2 o = make_float2(fmaxf(accx, 0.f), fmaxf(accy, 0.f));
    *(float2*)(out + (size_t)row * D_OUT + lane * 2) = o;
}

// ================== FALLBACK path (small workspace): round-7 pipeline ==================
__global__ __launch_bounds__(256) void hist_rows(const int* __restrict__ rows,
                                                 int* __restrict__ counts) {
    int i = blockIdx.x * 256 + threadIdx.x;
    if (i < N_EDGES / 4) {
        int4 r = *(const int4*)(rows + i * 4);
        atomicAdd(&counts[r.x], 1);
        atomicAdd(&counts[r.y], 1);
        atomicAdd(&counts[r.z], 1);
        atomicAdd(&counts[r.w], 1);
    }
}

#define SCHUNK 1024
#define NSCAN ((N_NODES + SCHUNK - 1) / SCHUNK)   /* 98 */
__global__ __launch_bounds__(1024) void scan_reduce(const int* __restrict__ counts,
                                                    int* __restrict__ bsum, int n) {
    __shared__ int ws[16];
    const int t = threadIdx.x, lane = t & 63, wid = t >> 6;
    int i = blockIdx.x * SCHUNK + t;
    int v = (i < n) ? counts[i] : 0;
#pragma unroll
    for (int off = 32; off >= 1; off >>= 1) v += __shfl_down(v, off);
    if (lane == 0) ws[wid] = v;
    __syncthreads();
    if (t == 0) {
        int s = 0;
#pragma unroll
        for (int w = 0; w < 16; ++w) s += ws[w];
        bsum[blockIdx.x] = s;
    }
}

__global__ __launch_bounds__(1024) void scan_apply(const int* __restrict__ counts,
                                                   const int* __restrict__ bsum,
                                                   int* __restrict__ ptr,
                                                   int* __restrict__ cursor, int n, int nb) {
    __shared__ int wtot[16];
    __shared__ int bpre[128];
    const int t = threadIdx.x, lane = t & 63, wid = t >> 6;
    int i = blockIdx.x * SCHUNK + t;
    int v = (i < n) ? counts[i] : 0;
    int x = v;
#pragma unroll
    for (int off = 1; off < 64; off <<= 1) {
        int u = __shfl_up(x, off);
        if (lane >= off) x += u;
    }
    if (lane == 63) wtot[wid] = x;

    if (wid == 0) {
        int carry = 0;
        for (int base = 0; base < nb; base += 64) {
            int idx = base + lane;
            int bv = (idx < nb) ? bsum[idx] : 0;
            int bx = bv;
#pragma unroll
            for (int off = 1; off < 64; off <<= 1) {
                int u = __shfl_up(bx, off);
                if (lane >= off) bx += u;
            }
            if (idx < nb) bpre[idx] = bx - bv + carry;
            carry += __shfl(bx, 63);
        }
    }
    __syncthreads();
    if (wid == 0) {
        int wv = (lane < 16) ? wtot[lane] : 0;
        int y = wv;
#pragma unroll
        for (int off = 1; off < 16; off <<= 1) {
            int u = __shfl_up(y, off);
            if (lane >= off) y += u;
        }
        if (lane < 16) wtot[lane] = y - wv;
    }
    __syncthreads();
    int excl = (x - v) + wtot[wid] + bpre[blockIdx.x];
    if (i < n) {
        ptr[i] = excl;
        cursor[i] = excl;
        if (i == n - 1) ptr[n] = excl + v;
    }
}

__global__ __launch_bounds__(256) void permute_edges(const int* __restrict__ rows,
                                                     const int* __restrict__ cols,
                                                     const float* __restrict__ vals,
                                                     int* __restrict__ cursor,
                                                     int2* __restrict__ edge_r) {
    const int w     = blockIdx.x & (NWIN - 1);
    const int slice = blockIdx.x >> 3;
    const int lo = w * ROWS_PER_WIN;
    const int hi = lo + ROWS_PER_WIN;
    const int per = (N_EDGES / 4) / PERM_SLICES;
    const int beg = slice * per;
    const int end = beg + per;
    for (int i = beg + (int)threadIdx.x; i < end; i += 256) {
        int4 r = *((const int4*)rows + i);
        const int e = i * 4;
        if (r.x >= lo && r.x < hi) {
            int p = atomicAdd(&cursor[r.x], 1);
            edge_r[p] = make_int2(cols[e + 0], __builtin_bit_cast(int, vals[e + 0]));
        }
        if (r.y >= lo && r.y < hi) {
            int p = atomicAdd(&cursor[r.y], 1);
            edge_r[p] = make_int2(cols[e + 1], __builtin_bit_cast(int, vals[e + 1]));
        }
        if (r.z >= lo && r.z < hi) {
            int p = atomicAdd(&cursor[r.z], 1);
            edge_r[p] = make_int2(cols[e + 2], __builtin_bit_cast(int, vals[e + 2]));
        }
        if (r.w >= lo && r.w < hi) {
            int p = atomicAdd(&cursor[r.w], 1);
            edge_r[p] = make_int2(cols[e + 3], __builtin_bit_cast(int, vals[e + 3]));
        }
    }
}

__global__ __launch_bounds__(256) void gather_rows(const int* __restrict__ ptr,
                                                   const int2* __restrict__ edge_r,
                                                   const unsigned short* __restrict__ hb,
                                                   float* __restrict__ out) {
    int row  = blockIdx.x * 4 + (threadIdx.x >> 6);
    int lane = threadIdx.x & 63;
    if (row >= N_NODES) return;
    int beg = __builtin_amdgcn_readfirstlane(ptr[row]);
    int end = __builtin_amdgcn_readfirstlane(ptr[row + 1]);

    float ax0 = 0.f, ay0 = 0.f, ax1 = 0.f, ay1 = 0.f;
    float ax2 = 0.f, ay2 = 0.f, ax3 = 0.f, ay3 = 0.f;
    int j = beg;
    for (; j + 4 <= end; j += 4) {
        int2 e0 = edge_r[j + 0];
        int2 e1 = edge_r[j + 1];
        int2 e2 = edge_r[j + 2];
        int2 e3 = edge_r[j + 3];
        unsigned int h0 = *(const unsigned int*)(hb + (size_t)e0.x * D_OUT + lane * 2);
        unsigned int h1 = *(const unsigned int*)(hb + (size_t)e1.x * D_OUT + lane * 2);
        unsigned int h2 = *(const unsigned int*)(hb + (size_t)e2.x * D_OUT + lane * 2);
        unsigned int h3 = *(const unsigned int*)(hb + (size_t)e3.x * D_OUT + lane * 2);
        float v0 = __builtin_bit_cast(float, e0.y);
        float v1 = __builtin_bit_cast(float, e1.y);
        float v2 = __builtin_bit_cast(float, e2.y);
        float v3 = __builtin_bit_cast(float, e3.y);
        ax0 = fmaf(v0, bf_lo(h0), ax0); ay0 = fmaf(v0, bf_hi(h0), ay0);
        ax1 = fmaf(v1, bf_lo(h1), ax1); ay1 = fmaf(v1, bf_hi(h1), ay1);
        ax2 = fmaf(v2, bf_lo(h2), ax2); ay2 = fmaf(v2, bf_hi(h2), ay2);
        ax3 = fmaf(v3, bf_lo(h3), ax3); ay3 = fmaf(v3, bf_hi(h3), ay3);
    }
    for (; j < end; ++j) {
        int2 e = edge_r[j];
        unsigned int h = *(const unsigned int*)(hb + (size_t)e.x * D_OUT + lane * 2);
        float v = __builtin_bit_cast(float, e.y);
        ax0 = fmaf(v, bf_lo(h), ax0);
        ay0 = fmaf(v, bf_hi(h), ay0);
    }
    float accx = (ax0 + ax1) + (ax2 + ax3);
    float accy = (ay0 + ay1) + (ay2 + ay3);
    float2 o = make_float2(fmaxf(accx, 0.f), fmaxf(accy, 0.f));
    *(float2*)(out + (size_t)row * D_OUT + lane * 2) = o;
}

extern "C" void kernel_launch(void* const* d_in, const int* in_sizes, int n_in,
                              void* d_out, int out_size, void* d_ws, size_t ws_size,
                              hipStream_t stream) {
    const float* x    = (const float*)d_in[0];
    const float* W    = (const float*)d_in[1];
    const int*   rows = (const int*)d_in[2];
    const int*   cols = (const int*)d_in[3];
    const float* vals = (const float*)d_in[4];
    float* out = (float*)d_out;

    char* ws = (char*)d_ws;
    size_t off = 0;
    unsigned short* hb  = (unsigned short*)(ws + off); off += ((size_t)N_NODES * D_OUT * 2 + 255) & ~(size_t)255;
    unsigned short* WbT = (unsigned short*)(ws + off); off += ((size_t)D_IN * D_OUT * 2 + 255) & ~(size_t)255;
    int*  cursor = (int*)(ws + off); off += ((size_t)N_NODES * 4 + 255) & ~(size_t)255;

    const size_t bucket_bytes = (size_t)N_NODES * CAP * 4;   // 25.6 MB (4B idx entries)

    if (ws_size >= off + bucket_bytes) {
        // ---- PRIMARY: padded-bucket idx-CSR, 4 dispatches ----
        int* buckets = (int*)(ws + off);
        convert_w<<<(D_IN * D_OUT) / 256, 256, 0, stream>>>(W, WbT, cursor, 1);
        gemm_mfma<<<GEMM_BLOCKS, 256, 0, stream>>>(x, WbT, hb);
        scatter_bucket<<<NWIN * PERM_SLICES, 256, 0, stream>>>(rows, cursor, buckets);
        gather_bucket<<<(N_NODES + 3) / 4, 256, 0, stream>>>(cursor, buckets, cols, vals, hb, out);
    } else {
        // ---- FALLBACK: hist + scan + permute (round-7 pipeline) ----
        int*  ptr    = (int*)(ws + off); size_t off2 = off + (((size_t)(N_NODES + 1) * 4 + 255) & ~(size_t)255);
        int2* edge_r = (int2*)(ws + off2); off2 += ((size_t)N_EDGES * 8 + 255) & ~(size_t)255;
        int*  bsum   = (int*)(ws + off2);

        convert_w<<<(D_IN * D_OUT) / 256, 256, 0, stream>>>(W, WbT, cursor, 0);
        gemm_mfma<<<GEMM_BLOCKS, 256, 0, stream>>>(x, WbT, hb);
        hist_rows<<<(N_EDGES / 4 + 255) / 256, 256, 0, stream>>>(rows, cursor);
        scan_reduce<<<NSCAN, 1024, 0, stream>>>(cursor, bsum, N_NODES);
        scan_apply<<<NSCAN, 1024, 0, stream>>>(cursor, bsum, ptr, cursor, N_NODES, NSCAN);
        permute_edges<<<NWIN * PERM_SLICES, 256, 0, stream>>>(rows, cols, vals, cursor, edge_r);
        gather_rows<<<(N_NODES + 3) / 4, 256, 0, stream>>>(ptr, edge_r, hb, out);
    }
}

// Round 10
// 383.444 us; speedup vs baseline: 1.0679x; 1.0679x over previous
//
#include <hip/hip_runtime.h>
#include <hip/hip_bf16.h>

#define N_NODES 100000
#define N_EDGES 1600000
#define D_IN 256
#define D_OUT 128
#define CAP 64            /* padded bucket capacity per row (max degree ~40) */

typedef short bf16x8 __attribute__((ext_vector_type(8)));
typedef float f32x4 __attribute__((ext_vector_type(4)));
typedef float f32x2 __attribute__((ext_vector_type(2)));

__device__ __forceinline__ unsigned short f2bf(float f) {
    unsigned int u = __builtin_bit_cast(unsigned int, f);
    u += 0x7fffu + ((u >> 16) & 1u);   // round-to-nearest-even
    return (unsigned short)(u >> 16);
}
__device__ __forceinline__ float bf_lo(unsigned int h) {
    return __builtin_bit_cast(float, h << 16);
}
__device__ __forceinline__ float bf_hi(unsigned int h) {
    return __builtin_bit_cast(float, h & 0xffff0000u);
}

// ---------- W transpose+convert + cursor init ----------
// bucket_mode: cursor[i] = i*CAP (padded-CSR base, int2-entry units); else 0.
__global__ __launch_bounds__(256) void convert_w(const float* __restrict__ W,
                                                 unsigned short* __restrict__ WbT,
                                                 int* __restrict__ cursor,
                                                 int bucket_mode) {
    int i = blockIdx.x * 256 + threadIdx.x;      // 32768 total
    int k = i >> 7;
    int n = i & 127;
    WbT[(size_t)n * D_IN + k] = f2bf(W[i]);
    int z = i * 4;                                // init 100000 ints (int4 stores)
    if (z < N_NODES) {
        int4 v = bucket_mode ? make_int4(z << 6, (z << 6) + CAP, (z << 6) + 2 * CAP, (z << 6) + 3 * CAP)
                             : make_int4(0, 0, 0, 0);
        *(int4*)(cursor + z) = v;
    }
}

// ---------- GEMM: hb = bf16(x @ W), MFMA 16x16x32, 16 rows/wave ----------
#define GEMM_BLOCKS ((N_NODES + 63) / 64)            /* 1563 */
__global__ __launch_bounds__(256) void gemm_mfma(const float* __restrict__ x,
                                                 const unsigned short* __restrict__ WbT,
                                                 unsigned short* __restrict__ hb) {
    const int wave = threadIdx.x >> 6;
    const int lane = threadIdx.x & 63;
    const int row0 = blockIdx.x * 64 + wave * 16;
    if (row0 >= N_NODES) return;                 // wave-uniform (100000 % 16 == 0)
    const int m = lane & 15;
    const int q = lane >> 4;

    const float* xr = x + (size_t)(row0 + m) * D_IN + q * 8;

    float4 a[8][2];
#pragma unroll
    for (int kc = 0; kc < 8; ++kc) {
        a[kc][0] = *(const float4*)(xr + kc * 32);
        a[kc][1] = *(const float4*)(xr + kc * 32 + 4);
    }

    bf16x8 af[8];
#pragma unroll
    for (int kc = 0; kc < 8; ++kc) {
        af[kc][0] = (short)f2bf(a[kc][0].x); af[kc][1] = (short)f2bf(a[kc][0].y);
        af[kc][2] = (short)f2bf(a[kc][0].z); af[kc][3] = (short)f2bf(a[kc][0].w);
        af[kc][4] = (short)f2bf(a[kc][1].x); af[kc][5] = (short)f2bf(a[kc][1].y);
        af[kc][6] = (short)f2bf(a[kc][1].z); af[kc][7] = (short)f2bf(a[kc][1].w);
    }

    f32x4 acc[8];
#pragma unroll
    for (int nt = 0; nt < 8; ++nt) acc[nt] = (f32x4){0.f, 0.f, 0.f, 0.f};

#pragma unroll
    for (int kc = 0; kc < 8; ++kc) {
        const int kb = kc * 32 + q * 8;
#pragma unroll
        for (int nt = 0; nt < 8; ++nt) {
            bf16x8 bf = *(const bf16x8*)(WbT + (size_t)(nt * 16 + m) * D_IN + kb);
            acc[nt] = __builtin_amdgcn_mfma_f32_16x16x32_bf16(af[kc], bf, acc[nt], 0, 0, 0);
        }
    }

    // D layout: row = q*4 + r, col = nt*16 + m
#pragma unroll
    for (int nt = 0; nt < 8; ++nt)
#pragma unroll
        for (int r = 0; r < 4; ++r) {
            int grow = row0 + q * 4 + r;
            hb[(size_t)grow * D_OUT + nt * 16 + m] = f2bf(acc[nt][r]);
        }
}

// ---------- PRIMARY: two-phase 16-window scatter of (col,val) into padded buckets ----------
// v3: 16 row-windows, TWO sequential passes per block (w8, then w8+8).
// Per-pass destination window = 6250*64*8 = 3.2MB < 4MiB XCD-L2, so 64B lines
// accumulate all 8 records before one full-line writeback (round-8's single
// 6.4MB window overflowed L2: WRITE stayed 95MB). All 2000 blocks co-resident
// (VGPR 12, 8 blk/CU cap >= grid) -> phase transition is ~synchronized, one
// window per XCD-L2 at a time. Pass 2 re-reads the block's 25.6KB rows slice
// from L1/L2 (near-free). 8B inline payload: gather needs NO cols/vals deref
// (round-9's 4B idx payload added 205MB of random 64B-line fetches in gather).
#define NWIN 16
#define ROWS_PER_WIN (N_NODES / NWIN)   /* 6250 */
#define PERM_SLICES 250                 /* 2000 blocks; 400000/250 = 1600 int4 per slice */
__global__ __launch_bounds__(256) void scatter_bucket(const int* __restrict__ rows,
                                                      const int* __restrict__ cols,
                                                      const float* __restrict__ vals,
                                                      int* __restrict__ cursor,
                                                      int2* __restrict__ buckets) {
    const int w8    = blockIdx.x & 7;
    const int slice = blockIdx.x >> 3;          // 0..249
    const int per = (N_EDGES / 4) / PERM_SLICES;  // 1600
    const int beg = slice * per;
    const int end = beg + per;
#pragma unroll
    for (int ph = 0; ph < 2; ++ph) {
        const int lo = (w8 + ph * 8) * ROWS_PER_WIN;
        const int hi = lo + ROWS_PER_WIN;
        for (int i = beg + (int)threadIdx.x; i < end; i += 256) {
            int4 r = *((const int4*)rows + i);
            const int e = i * 4;
            if (r.x >= lo && r.x < hi) {
                int p = atomicAdd(&cursor[r.x], 1);
                buckets[p] = make_int2(cols[e + 0], __builtin_bit_cast(int, vals[e + 0]));
            }
            if (r.y >= lo && r.y < hi) {
                int p = atomicAdd(&cursor[r.y], 1);
                buckets[p] = make_int2(cols[e + 1], __builtin_bit_cast(int, vals[e + 1]));
            }
            if (r.z >= lo && r.z < hi) {
                int p = atomicAdd(&cursor[r.z], 1);
                buckets[p] = make_int2(cols[e + 2], __builtin_bit_cast(int, vals[e + 2]));
            }
            if (r.w >= lo && r.w < hi) {
                int p = atomicAdd(&cursor[r.w], 1);
                buckets[p] = make_int2(cols[e + 3], __builtin_bit_cast(int, vals[e + 3]));
            }
        }
    }
}

// ---------- PRIMARY gather: beg = row*CAP (free), end = cursor[row] ----------
// int4 paired bucket loads (2 edges / 16B load, 32B-aligned); nt store keeps
// the 51.2MB out-stream from evicting hb lines in L2.
__global__ __launch_bounds__(256) void gather_bucket(const int* __restrict__ cursor,
                                                     const int2* __restrict__ buckets,
                                                     const unsigned short* __restrict__ hb,
                                                     float* __restrict__ out) {
    int row  = blockIdx.x * 4 + (threadIdx.x >> 6);
    int lane = threadIdx.x & 63;
    if (row >= N_NODES) return;
    int beg = row << 6;                                            // row*CAP
    int end = __builtin_amdgcn_readfirstlane(cursor[row]);

    float ax0 = 0.f, ay0 = 0.f, ax1 = 0.f, ay1 = 0.f;
    float ax2 = 0.f, ay2 = 0.f, ax3 = 0.f, ay3 = 0.f;
    int j = beg;
    for (; j + 4 <= end; j += 4) {
        int4 p01 = *(const int4*)(buckets + j);        // edges j, j+1
        int4 p23 = *(const int4*)(buckets + j + 2);    // edges j+2, j+3
        unsigned int h0 = *(const unsigned int*)(hb + (size_t)p01.x * D_OUT + lane * 2);
        unsigned int h1 = *(const unsigned int*)(hb + (size_t)p01.z * D_OUT + lane * 2);
        unsigned int h2 = *(const unsigned int*)(hb + (size_t)p23.x * D_OUT + lane * 2);
        unsigned int h3 = *(const unsigned int*)(hb + (size_t)p23.z * D_OUT + lane * 2);
        float v0 = __builtin_bit_cast(float, p01.y);
        float v1 = __builtin_bit_cast(float, p01.w);
        float v2 = __builtin_bit_cast(float, p23.y);
        float v3 = __builtin_bit_cast(float, p23.w);
        ax0 = fmaf(v0, bf_lo(h0), ax0); ay0 = fmaf(v0, bf_hi(h0), ay0);
        ax1 = fmaf(v1, bf_lo(h1), ax1); ay1 = fmaf(v1, bf_hi(h1), ay1);
        ax2 = fmaf(v2, bf_lo(h2), ax2); ay2 = fmaf(v2, bf_hi(h2), ay2);
        ax3 = fmaf(v3, bf_lo(h3), ax3); ay3 = fmaf(v3, bf_hi(h3), ay3);
    }
    for (; j < end; ++j) {
        int2 e = buckets[j];
        unsigned int h = *(const unsigned int*)(hb + (size_t)e.x * D_OUT + lane * 2);
        float v = __builtin_bit_cast(float, e.y);
        ax0 = fmaf(v, bf_lo(h), ax0);
        ay0 = fmaf(v, bf_hi(h), ay0);
    }
    float accx = (ax0 + ax1) + (ax2 + ax3);
    float accy = (ay0 + ay1) + (ay2 + ay3);
    f32x2 o;
    o[0] = fmaxf(accx, 0.f);
    o[1] = fmaxf(accy, 0.f);
    __builtin_nontemporal_store(o, (f32x2*)(out + (size_t)row * D_OUT + lane * 2));
}

// ================== FALLBACK path (small workspace): round-7 pipeline ==================
__global__ __launch_bounds__(256) void hist_rows(const int* __restrict__ rows,
                                                 int* __restrict__ counts) {
    int i = blockIdx.x * 256 + threadIdx.x;
    if (i < N_EDGES / 4) {
        int4 r = *(const int4*)(rows + i * 4);
        atomicAdd(&counts[r.x], 1);
        atomicAdd(&counts[r.y], 1);
        atomicAdd(&counts[r.z], 1);
        atomicAdd(&counts[r.w], 1);
    }
}

#define SCHUNK 1024
#define NSCAN ((N_NODES + SCHUNK - 1) / SCHUNK)   /* 98 */
__global__ __launch_bounds__(1024) void scan_reduce(const int* __restrict__ counts,
                                                    int* __restrict__ bsum, int n) {
    __shared__ int ws[16];
    const int t = threadIdx.x, lane = t & 63, wid = t >> 6;
    int i = blockIdx.x * SCHUNK + t;
    int v = (i < n) ? counts[i] : 0;
#pragma unroll
    for (int off = 32; off >= 1; off >>= 1) v += __shfl_down(v, off);
    if (lane == 0) ws[wid] = v;
    __syncthreads();
    if (t == 0) {
        int s = 0;
#pragma unroll
        for (int w = 0; w < 16; ++w) s += ws[w];
        bsum[blockIdx.x] = s;
    }
}

__global__ __launch_bounds__(1024) void scan_apply(const int* __restrict__ counts,
                                                   const int* __restrict__ bsum,
                                                   int* __restrict__ ptr,
                                                   int* __restrict__ cursor, int n, int nb) {
    __shared__ int wtot[16];
    __shared__ int bpre[128];
    const int t = threadIdx.x, lane = t & 63, wid = t >> 6;
    int i = blockIdx.x * SCHUNK + t;
    int v = (i < n) ? counts[i] : 0;
    int x = v;
#pragma unroll
    for (int off = 1; off < 64; off <<= 1) {
        int u = __shfl_up(x, off);
        if (lane >= off) x += u;
    }
    if (lane == 63) wtot[wid] = x;

    if (wid == 0) {
        int carry = 0;
        for (int base = 0; base < nb; base += 64) {
            int idx = base + lane;
            int bv = (idx < nb) ? bsum[idx] : 0;
            int bx = bv;
#pragma unroll
            for (int off = 1; off < 64; off <<= 1) {
                int u = __shfl_up(bx, off);
                if (lane >= off) bx += u;
            }
            if (idx < nb) bpre[idx] = bx - bv + carry;
            carry += __shfl(bx, 63);
        }
    }
    __syncthreads();
    if (wid == 0) {
        int wv = (lane < 16) ? wtot[lane] : 0;
        int y = wv;
#pragma unroll
        for (int off = 1; off < 16; off <<= 1) {
            int u = __shfl_up(y, off);
            if (lane >= off) y += u;
        }
        if (lane < 16) wtot[lane] = y - wv;
    }
    __syncthreads();
    int excl = (x - v) + wtot[wid] + bpre[blockIdx.x];
    if (i < n) {
        ptr[i] = excl;
        cursor[i] = excl;
        if (i == n - 1) ptr[n] = excl + v;
    }
}

__global__ __launch_bounds__(256) void permute_edges(const int* __restrict__ rows,
                                                     const int* __restrict__ cols,
                                                     const float* __restrict__ vals,
                                                     int* __restrict__ cursor,
                                                     int2* __restrict__ edge_r) {
    const int w     = blockIdx.x & 7;
    const int slice = blockIdx.x >> 3;
    const int lo = w * (N_NODES / 8);
    const int hi = lo + (N_NODES / 8);
    const int per = (N_EDGES / 4) / PERM_SLICES;
    const int beg = slice * per;
    const int end = beg + per;
    for (int i = beg + (int)threadIdx.x; i < end; i += 256) {
        int4 r = *((const int4*)rows + i);
        const int e = i * 4;
        if (r.x >= lo && r.x < hi) {
            int p = atomicAdd(&cursor[r.x], 1);
            edge_r[p] = make_int2(cols[e + 0], __builtin_bit_cast(int, vals[e + 0]));
        }
        if (r.y >= lo && r.y < hi) {
            int p = atomicAdd(&cursor[r.y], 1);
            edge_r[p] = make_int2(cols[e + 1], __builtin_bit_cast(int, vals[e + 1]));
        }
        if (r.z >= lo && r.z < hi) {
            int p = atomicAdd(&cursor[r.z], 1);
            edge_r[p] = make_int2(cols[e + 2], __builtin_bit_cast(int, vals[e + 2]));
        }
        if (r.w >= lo && r.w < hi) {
            int p = atomicAdd(&cursor[r.w], 1);
            edge_r[p] = make_int2(cols[e + 3], __builtin_bit_cast(int, vals[e + 3]));
        }
    }
}

__global__ __launch_bounds__(256) void gather_rows(const int* __restrict__ ptr,
                                                   const int2* __restrict__ edge_r,
                                                   const unsigned short* __restrict__ hb,
                                                   float* __restrict__ out) {
    int row  = blockIdx.x * 4 + (threadIdx.x >> 6);
    int lane = threadIdx.x & 63;
    if (row >= N_NODES) return;
    int beg = __builtin_amdgcn_readfirstlane(ptr[row]);
    int end = __builtin_amdgcn_readfirstlane(ptr[row + 1]);

    float ax0 = 0.f, ay0 = 0.f, ax1 = 0.f, ay1 = 0.f;
    float ax2 = 0.f, ay2 = 0.f, ax3 = 0.f, ay3 = 0.f;
    int j = beg;
    for (; j + 4 <= end; j += 4) {
        int2 e0 = edge_r[j + 0];
        int2 e1 = edge_r[j + 1];
        int2 e2 = edge_r[j + 2];
        int2 e3 = edge_r[j + 3];
        unsigned int h0 = *(const unsigned int*)(hb + (size_t)e0.x * D_OUT + lane * 2);
        unsigned int h1 = *(const unsigned int*)(hb + (size_t)e1.x * D_OUT + lane * 2);
        unsigned int h2 = *(const unsigned int*)(hb + (size_t)e2.x * D_OUT + lane * 2);
        unsigned int h3 = *(const unsigned int*)(hb + (size_t)e3.x * D_OUT + lane * 2);
        float v0 = __builtin_bit_cast(float, e0.y);
        float v1 = __builtin_bit_cast(float, e1.y);
        float v2 = __builtin_bit_cast(float, e2.y);
        float v3 = __builtin_bit_cast(float, e3.y);
        ax0 = fmaf(v0, bf_lo(h0), ax0); ay0 = fmaf(v0, bf_hi(h0), ay0);
        ax1 = fmaf(v1, bf_lo(h1), ax1); ay1 = fmaf(v1, bf_hi(h1), ay1);
        ax2 = fmaf(v2, bf_lo(h2), ax2); ay2 = fmaf(v2, bf_hi(h2), ay2);
        ax3 = fmaf(v3, bf_lo(h3), ax3); ay3 = fmaf(v3, bf_hi(h3), ay3);
    }
    for (; j < end; ++j) {
        int2 e = edge_r[j];
        unsigned int h = *(const unsigned int*)(hb + (size_t)e.x * D_OUT + lane * 2);
        float v = __builtin_bit_cast(float, e.y);
        ax0 = fmaf(v, bf_lo(h), ax0);
        ay0 = fmaf(v, bf_hi(h), ay0);
    }
    float accx = (ax0 + ax1) + (ax2 + ax3);
    float accy = (ay0 + ay1) + (ay2 + ay3);
    float2 o = make_float2(fmaxf(accx, 0.f), fmaxf(accy, 0.f));
    *(float2*)(out + (size_t)row * D_OUT + lane * 2) = o;
}

extern "C" void kernel_launch(void* const* d_in, const int* in_sizes, int n_in,
                              void* d_out, int out_size, void* d_ws, size_t ws_size,
                              hipStream_t stream) {
    const float* x    = (const float*)d_in[0];
    const float* W    = (const float*)d_in[1];
    const int*   rows = (const int*)d_in[2];
    const int*   cols = (const int*)d_in[3];
    const float* vals = (const float*)d_in[4];
    float* out = (float*)d_out;

    char* ws = (char*)d_ws;
    size_t off = 0;
    unsigned short* hb  = (unsigned short*)(ws + off); off += ((size_t)N_NODES * D_OUT * 2 + 255) & ~(size_t)255;
    unsigned short* WbT = (unsigned short*)(ws + off); off += ((size_t)D_IN * D_OUT * 2 + 255) & ~(size_t)255;
    int*  cursor = (int*)(ws + off); off += ((size_t)N_NODES * 4 + 255) & ~(size_t)255;

    const size_t bucket_bytes = (size_t)N_NODES * CAP * 8;   // 51.2 MB (int2 entries)

    if (ws_size >= off + bucket_bytes) {
        // ---- PRIMARY: padded-bucket CSR, 4 dispatches ----
        int2* buckets = (int2*)(ws + off);
        convert_w<<<(D_IN * D_OUT) / 256, 256, 0, stream>>>(W, WbT, cursor, 1);
        gemm_mfma<<<GEMM_BLOCKS, 256, 0, stream>>>(x, WbT, hb);
        scatter_bucket<<<8 * PERM_SLICES, 256, 0, stream>>>(rows, cols, vals, cursor, buckets);
        gather_bucket<<<(N_NODES + 3) / 4, 256, 0, stream>>>(cursor, buckets, hb, out);
    } else {
        // ---- FALLBACK: hist + scan + permute (round-7 pipeline) ----
        int*  ptr    = (int*)(ws + off); size_t off2 = off + (((size_t)(N_NODES + 1) * 4 + 255) & ~(size_t)255);
        int2* edge_r = (int2*)(ws + off2); off2 += ((size_t)N_EDGES * 8 + 255) & ~(size_t)255;
        int*  bsum   = (int*)(ws + off2);

        convert_w<<<(D_IN * D_OUT) / 256, 256, 0, stream>>>(W, WbT, cursor, 0);
        gemm_mfma<<<GEMM_BLOCKS, 256, 0, stream>>>(x, WbT, hb);
        hist_rows<<<(N_EDGES / 4 + 255) / 256, 256, 0, stream>>>(rows, cursor);
        scan_reduce<<<NSCAN, 1024, 0, stream>>>(cursor, bsum, N_NODES);
        scan_apply<<<NSCAN, 1024, 0, stream>>>(cursor, bsum, ptr, cursor, N_NODES, NSCAN);
        permute_edges<<<8 * PERM_SLICES, 256, 0, stream>>>(rows, cols, vals, cursor, edge_r);
        gather_rows<<<(N_NODES + 3) / 4, 256, 0, stream>>>(ptr, edge_r, hb, out);
    }
}

// Round 11
// 374.950 us; speedup vs baseline: 1.0921x; 1.0227x over previous
//
#include <hip/hip_runtime.h>
#include <hip/hip_bf16.h>

#define N_NODES 100000
#define N_EDGES 1600000
#define D_IN 256
#define D_OUT 128
#define CAP 64            /* padded bucket capacity per row (max degree ~40) */

typedef short bf16x8 __attribute__((ext_vector_type(8)));
typedef float f32x4 __attribute__((ext_vector_type(4)));
typedef float f32x2 __attribute__((ext_vector_type(2)));

__device__ __forceinline__ unsigned short f2bf(float f) {
    unsigned int u = __builtin_bit_cast(unsigned int, f);
    u += 0x7fffu + ((u >> 16) & 1u);   // round-to-nearest-even
    return (unsigned short)(u >> 16);
}
__device__ __forceinline__ float bf_lo(unsigned int h) {
    return __builtin_bit_cast(float, h << 16);
}
__device__ __forceinline__ float bf_hi(unsigned int h) {
    return __builtin_bit_cast(float, h & 0xffff0000u);
}

// ---------- W transpose+convert + cursor init ----------
// bucket_mode: cursor[i] = i*CAP (padded-CSR base); else 0.
__global__ __launch_bounds__(256) void convert_w(const float* __restrict__ W,
                                                 unsigned short* __restrict__ WbT,
                                                 int* __restrict__ cursor,
                                                 int bucket_mode) {
    int i = blockIdx.x * 256 + threadIdx.x;      // 32768 total
    int k = i >> 7;
    int n = i & 127;
    WbT[(size_t)n * D_IN + k] = f2bf(W[i]);
    int z = i * 4;                                // init 100000 ints (int4 stores)
    if (z < N_NODES) {
        int4 v = bucket_mode ? make_int4(z << 6, (z << 6) + CAP, (z << 6) + 2 * CAP, (z << 6) + 3 * CAP)
                             : make_int4(0, 0, 0, 0);
        *(int4*)(cursor + z) = v;
    }
}

// ---------- FUSED gemm + scatter (grid-partitioned, independent work) ----------
// gemm is latency-bound (HBM 13%, MFMA 2%); scatter is atomic/write-bound
// (HBM 32%). They share no data -> co-scheduling lets each fill the other's
// idle memory slots. Scatter is the proven single-pass 8-window form (r8:
// 89us, FETCH 79MB; r10's two-phase refuted the L2-merge theory: WRITE
// unchanged, FETCH +60MB). ~50MB of scatter WRITE is structural atomic-RMW.
#define GEMM_BLOCKS ((N_NODES + 63) / 64)            /* 1563 */
#define NWIN 8
#define ROWS_PER_WIN (N_NODES / NWIN)   /* 12500 */
#define PERM_SLICES 250                 /* 2000 scatter blocks */
__global__ __launch_bounds__(256) void gemm_scatter(const float* __restrict__ x,
                                                    const unsigned short* __restrict__ WbT,
                                                    unsigned short* __restrict__ hb,
                                                    const int* __restrict__ rows,
                                                    const int* __restrict__ cols,
                                                    const float* __restrict__ vals,
                                                    int* __restrict__ cursor,
                                                    int2* __restrict__ buckets) {
    if (blockIdx.x >= GEMM_BLOCKS) {
        const int s     = blockIdx.x - GEMM_BLOCKS;
        const int w     = s & (NWIN - 1);
        const int slice = s >> 3;                     // 0..249
        const int lo = w * ROWS_PER_WIN;
        const int hi = lo + ROWS_PER_WIN;
        const int per = (N_EDGES / 4) / PERM_SLICES;  // 1600
        const int beg = slice * per;
        const int end = beg + per;
        for (int i = beg + (int)threadIdx.x; i < end; i += 256) {
            int4 r = *((const int4*)rows + i);
            const int e = i * 4;
            if (r.x >= lo && r.x < hi) {
                int p = atomicAdd(&cursor[r.x], 1);
                buckets[p] = make_int2(cols[e + 0], __builtin_bit_cast(int, vals[e + 0]));
            }
            if (r.y >= lo && r.y < hi) {
                int p = atomicAdd(&cursor[r.y], 1);
                buckets[p] = make_int2(cols[e + 1], __builtin_bit_cast(int, vals[e + 1]));
            }
            if (r.z >= lo && r.z < hi) {
                int p = atomicAdd(&cursor[r.z], 1);
                buckets[p] = make_int2(cols[e + 2], __builtin_bit_cast(int, vals[e + 2]));
            }
            if (r.w >= lo && r.w < hi) {
                int p = atomicAdd(&cursor[r.w], 1);
                buckets[p] = make_int2(cols[e + 3], __builtin_bit_cast(int, vals[e + 3]));
            }
        }
        return;
    }

    // ---- gemm half: hb = bf16(x @ W), MFMA 16x16x32, 16 rows/wave ----
    const int wave = threadIdx.x >> 6;
    const int lane = threadIdx.x & 63;
    const int row0 = blockIdx.x * 64 + wave * 16;
    if (row0 >= N_NODES) return;                 // wave-uniform (100000 % 16 == 0)
    const int m = lane & 15;
    const int q = lane >> 4;

    const float* xr = x + (size_t)(row0 + m) * D_IN + q * 8;

    float4 a[8][2];
#pragma unroll
    for (int kc = 0; kc < 8; ++kc) {
        a[kc][0] = *(const float4*)(xr + kc * 32);
        a[kc][1] = *(const float4*)(xr + kc * 32 + 4);
    }

    bf16x8 af[8];
#pragma unroll
    for (int kc = 0; kc < 8; ++kc) {
        af[kc][0] = (short)f2bf(a[kc][0].x); af[kc][1] = (short)f2bf(a[kc][0].y);
        af[kc][2] = (short)f2bf(a[kc][0].z); af[kc][3] = (short)f2bf(a[kc][0].w);
        af[kc][4] = (short)f2bf(a[kc][1].x); af[kc][5] = (short)f2bf(a[kc][1].y);
        af[kc][6] = (short)f2bf(a[kc][1].z); af[kc][7] = (short)f2bf(a[kc][1].w);
    }

    f32x4 acc[8];
#pragma unroll
    for (int nt = 0; nt < 8; ++nt) acc[nt] = (f32x4){0.f, 0.f, 0.f, 0.f};

#pragma unroll
    for (int kc = 0; kc < 8; ++kc) {
        const int kb = kc * 32 + q * 8;
#pragma unroll
        for (int nt = 0; nt < 8; ++nt) {
            bf16x8 bf = *(const bf16x8*)(WbT + (size_t)(nt * 16 + m) * D_IN + kb);
            acc[nt] = __builtin_amdgcn_mfma_f32_16x16x32_bf16(af[kc], bf, acc[nt], 0, 0, 0);
        }
    }

    // D layout: row = q*4 + r, col = nt*16 + m
#pragma unroll
    for (int nt = 0; nt < 8; ++nt)
#pragma unroll
        for (int r = 0; r < 4; ++r) {
            int grow = row0 + q * 4 + r;
            hb[(size_t)grow * D_OUT + nt * 16 + m] = f2bf(acc[nt][r]);
        }
}

// ---------- gather: beg = row*CAP (free), end = cursor[row] ----------
__global__ __launch_bounds__(256) void gather_bucket(const int* __restrict__ cursor,
                                                     const int2* __restrict__ buckets,
                                                     const unsigned short* __restrict__ hb,
                                                     float* __restrict__ out) {
    int row  = blockIdx.x * 4 + (threadIdx.x >> 6);
    int lane = threadIdx.x & 63;
    if (row >= N_NODES) return;
    int beg = row << 6;                                            // row*CAP
    int end = __builtin_amdgcn_readfirstlane(cursor[row]);

    float ax0 = 0.f, ay0 = 0.f, ax1 = 0.f, ay1 = 0.f;
    float ax2 = 0.f, ay2 = 0.f, ax3 = 0.f, ay3 = 0.f;
    int j = beg;
    for (; j + 4 <= end; j += 4) {
        int4 p01 = *(const int4*)(buckets + j);        // edges j, j+1
        int4 p23 = *(const int4*)(buckets + j + 2);    // edges j+2, j+3
        unsigned int h0 = *(const unsigned int*)(hb + (size_t)p01.x * D_OUT + lane * 2);
        unsigned int h1 = *(const unsigned int*)(hb + (size_t)p01.z * D_OUT + lane * 2);
        unsigned int h2 = *(const unsigned int*)(hb + (size_t)p23.x * D_OUT + lane * 2);
        unsigned int h3 = *(const unsigned int*)(hb + (size_t)p23.z * D_OUT + lane * 2);
        float v0 = __builtin_bit_cast(float, p01.y);
        float v1 = __builtin_bit_cast(float, p01.w);
        float v2 = __builtin_bit_cast(float, p23.y);
        float v3 = __builtin_bit_cast(float, p23.w);
        ax0 = fmaf(v0, bf_lo(h0), ax0); ay0 = fmaf(v0, bf_hi(h0), ay0);
        ax1 = fmaf(v1, bf_lo(h1), ax1); ay1 = fmaf(v1, bf_hi(h1), ay1);
        ax2 = fmaf(v2, bf_lo(h2), ax2); ay2 = fmaf(v2, bf_hi(h2), ay2);
        ax3 = fmaf(v3, bf_lo(h3), ax3); ay3 = fmaf(v3, bf_hi(h3), ay3);
    }
    for (; j < end; ++j) {
        int2 e = buckets[j];
        unsigned int h = *(const unsigned int*)(hb + (size_t)e.x * D_OUT + lane * 2);
        float v = __builtin_bit_cast(float, e.y);
        ax0 = fmaf(v, bf_lo(h), ax0);
        ay0 = fmaf(v, bf_hi(h), ay0);
    }
    float accx = (ax0 + ax1) + (ax2 + ax3);
    float accy = (ay0 + ay1) + (ay2 + ay3);
    f32x2 o;
    o[0] = fmaxf(accx, 0.f);
    o[1] = fmaxf(accy, 0.f);
    __builtin_nontemporal_store(o, (f32x2*)(out + (size_t)row * D_OUT + lane * 2));
}

// ================== FALLBACK path (small workspace): round-7 pipeline ==================
__global__ __launch_bounds__(256) void gemm_mfma(const float* __restrict__ x,
                                                 const unsigned short* __restrict__ WbT,
                                                 unsigned short* __restrict__ hb) {
    const int wave = threadIdx.x >> 6;
    const int lane = threadIdx.x & 63;
    const int row0 = blockIdx.x * 64 + wave * 16;
    if (row0 >= N_NODES) return;
    const int m = lane & 15;
    const int q = lane >> 4;

    const float* xr = x + (size_t)(row0 + m) * D_IN + q * 8;

    float4 a[8][2];
#pragma unroll
    for (int kc = 0; kc < 8; ++kc) {
        a[kc][0] = *(const float4*)(xr + kc * 32);
        a[kc][1] = *(const float4*)(xr + kc * 32 + 4);
    }

    bf16x8 af[8];
#pragma unroll
    for (int kc = 0; kc < 8; ++kc) {
        af[kc][0] = (short)f2bf(a[kc][0].x); af[kc][1] = (short)f2bf(a[kc][0].y);
        af[kc][2] = (short)f2bf(a[kc][0].z); af[kc][3] = (short)f2bf(a[kc][0].w);
        af[kc][4] = (short)f2bf(a[kc][1].x); af[kc][5] = (short)f2bf(a[kc][1].y);
        af[kc][6] = (short)f2bf(a[kc][1].z); af[kc][7] = (short)f2bf(a[kc][1].w);
    }

    f32x4 acc[8];
#pragma unroll
    for (int nt = 0; nt < 8; ++nt) acc[nt] = (f32x4){0.f, 0.f, 0.f, 0.f};

#pragma unroll
    for (int kc = 0; kc < 8; ++kc) {
        const int kb = kc * 32 + q * 8;
#pragma unroll
        for (int nt = 0; nt < 8; ++nt) {
            bf16x8 bf = *(const bf16x8*)(WbT + (size_t)(nt * 16 + m) * D_IN + kb);
            acc[nt] = __builtin_amdgcn_mfma_f32_16x16x32_bf16(af[kc], bf, acc[nt], 0, 0, 0);
        }
    }

#pragma unroll
    for (int nt = 0; nt < 8; ++nt)
#pragma unroll
        for (int r = 0; r < 4; ++r) {
            int grow = row0 + q * 4 + r;
            hb[(size_t)grow * D_OUT + nt * 16 + m] = f2bf(acc[nt][r]);
        }
}

__global__ __launch_bounds__(256) void hist_rows(const int* __restrict__ rows,
                                                 int* __restrict__ counts) {
    int i = blockIdx.x * 256 + threadIdx.x;
    if (i < N_EDGES / 4) {
        int4 r = *(const int4*)(rows + i * 4);
        atomicAdd(&counts[r.x], 1);
        atomicAdd(&counts[r.y], 1);
        atomicAdd(&counts[r.z], 1);
        atomicAdd(&counts[r.w], 1);
    }
}

#define SCHUNK 1024
#define NSCAN ((N_NODES + SCHUNK - 1) / SCHUNK)   /* 98 */
__global__ __launch_bounds__(1024) void scan_reduce(const int* __restrict__ counts,
                                                    int* __restrict__ bsum, int n) {
    __shared__ int ws[16];
    const int t = threadIdx.x, lane = t & 63, wid = t >> 6;
    int i = blockIdx.x * SCHUNK + t;
    int v = (i < n) ? counts[i] : 0;
#pragma unroll
    for (int off = 32; off >= 1; off >>= 1) v += __shfl_down(v, off);
    if (lane == 0) ws[wid] = v;
    __syncthreads();
    if (t == 0) {
        int s = 0;
#pragma unroll
        for (int w = 0; w < 16; ++w) s += ws[w];
        bsum[blockIdx.x] = s;
    }
}

__global__ __launch_bounds__(1024) void scan_apply(const int* __restrict__ counts,
                                                   const int* __restrict__ bsum,
                                                   int* __restrict__ ptr,
                                                   int* __restrict__ cursor, int n, int nb) {
    __shared__ int wtot[16];
    __shared__ int bpre[128];
    const int t = threadIdx.x, lane = t & 63, wid = t >> 6;
    int i = blockIdx.x * SCHUNK + t;
    int v = (i < n) ? counts[i] : 0;
    int x = v;
#pragma unroll
    for (int off = 1; off < 64; off <<= 1) {
        int u = __shfl_up(x, off);
        if (lane >= off) x += u;
    }
    if (lane == 63) wtot[wid] = x;

    if (wid == 0) {
        int carry = 0;
        for (int base = 0; base < nb; base += 64) {
            int idx = base + lane;
            int bv = (idx < nb) ? bsum[idx] : 0;
            int bx = bv;
#pragma unroll
            for (int off = 1; off < 64; off <<= 1) {
                int u = __shfl_up(bx, off);
                if (lane >= off) bx += u;
            }
            if (idx < nb) bpre[idx] = bx - bv + carry;
            carry += __shfl(bx, 63);
        }
    }
    __syncthreads();
    if (wid == 0) {
        int wv = (lane < 16) ? wtot[lane] : 0;
        int y = wv;
#pragma unroll
        for (int off = 1; off < 16; off <<= 1) {
            int u = __shfl_up(y, off);
            if (lane >= off) y += u;
        }
        if (lane < 16) wtot[lane] = y - wv;
    }
    __syncthreads();
    int excl = (x - v) + wtot[wid] + bpre[blockIdx.x];
    if (i < n) {
        ptr[i] = excl;
        cursor[i] = excl;
        if (i == n - 1) ptr[n] = excl + v;
    }
}

__global__ __launch_bounds__(256) void permute_edges(const int* __restrict__ rows,
                                                     const int* __restrict__ cols,
                                                     const float* __restrict__ vals,
                                                     int* __restrict__ cursor,
                                                     int2* __restrict__ edge_r) {
    const int w     = blockIdx.x & 7;
    const int slice = blockIdx.x >> 3;
    const int lo = w * (N_NODES / 8);
    const int hi = lo + (N_NODES / 8);
    const int per = (N_EDGES / 4) / PERM_SLICES;
    const int beg = slice * per;
    const int end = beg + per;
    for (int i = beg + (int)threadIdx.x; i < end; i += 256) {
        int4 r = *((const int4*)rows + i);
        const int e = i * 4;
        if (r.x >= lo && r.x < hi) {
            int p = atomicAdd(&cursor[r.x], 1);
            edge_r[p] = make_int2(cols[e + 0], __builtin_bit_cast(int, vals[e + 0]));
        }
        if (r.y >= lo && r.y < hi) {
            int p = atomicAdd(&cursor[r.y], 1);
            edge_r[p] = make_int2(cols[e + 1], __builtin_bit_cast(int, vals[e + 1]));
        }
        if (r.z >= lo && r.z < hi) {
            int p = atomicAdd(&cursor[r.z], 1);
            edge_r[p] = make_int2(cols[e + 2], __builtin_bit_cast(int, vals[e + 2]));
        }
        if (r.w >= lo && r.w < hi) {
            int p = atomicAdd(&cursor[r.w], 1);
            edge_r[p] = make_int2(cols[e + 3], __builtin_bit_cast(int, vals[e + 3]));
        }
    }
}

__global__ __launch_bounds__(256) void gather_rows(const int* __restrict__ ptr,
                                                   const int2* __restrict__ edge_r,
                                                   const unsigned short* __restrict__ hb,
                                                   float* __restrict__ out) {
    int row  = blockIdx.x * 4 + (threadIdx.x >> 6);
    int lane = threadIdx.x & 63;
    if (row >= N_NODES) return;
    int beg = __builtin_amdgcn_readfirstlane(ptr[row]);
    int end = __builtin_amdgcn_readfirstlane(ptr[row + 1]);

    float ax0 = 0.f, ay0 = 0.f, ax1 = 0.f, ay1 = 0.f;
    float ax2 = 0.f, ay2 = 0.f, ax3 = 0.f, ay3 = 0.f;
    int j = beg;
    for (; j + 4 <= end; j += 4) {
        int2 e0 = edge_r[j + 0];
        int2 e1 = edge_r[j + 1];
        int2 e2 = edge_r[j + 2];
        int2 e3 = edge_r[j + 3];
        unsigned int h0 = *(const unsigned int*)(hb + (size_t)e0.x * D_OUT + lane * 2);
        unsigned int h1 = *(const unsigned int*)(hb + (size_t)e1.x * D_OUT + lane * 2);
        unsigned int h2 = *(const unsigned int*)(hb + (size_t)e2.x * D_OUT + lane * 2);
        unsigned int h3 = *(const unsigned int*)(hb + (size_t)e3.x * D_OUT + lane * 2);
        float v0 = __builtin_bit_cast(float, e0.y);
        float v1 = __builtin_bit_cast(float, e1.y);
        float v2 = __builtin_bit_cast(float, e2.y);
        float v3 = __builtin_bit_cast(float, e3.y);
        ax0 = fmaf(v0, bf_lo(h0), ax0); ay0 = fmaf(v0, bf_hi(h0), ay0);
        ax1 = fmaf(v1, bf_lo(h1), ax1); ay1 = fmaf(v1, bf_hi(h1), ay1);
        ax2 = fmaf(v2, bf_lo(h2), ax2); ay2 = fmaf(v2, bf_hi(h2), ay2);
        ax3 = fmaf(v3, bf_lo(h3), ax3); ay3 = fmaf(v3, bf_hi(h3), ay3);
    }
    for (; j < end; ++j) {
        int2 e = edge_r[j];
        unsigned int h = *(const unsigned int*)(hb + (size_t)e.x * D_OUT + lane * 2);
        float v = __builtin_bit_cast(float, e.y);
        ax0 = fmaf(v, bf_lo(h), ax0);
        ay0 = fmaf(v, bf_hi(h), ay0);
    }
    float accx = (ax0 + ax1) + (ax2 + ax3);
    float accy = (ay0 + ay1) + (ay2 + ay3);
    float2 o = make_float2(fmaxf(accx, 0.f), fmaxf(accy, 0.f));
    *(float2*)(out + (size_t)row * D_OUT + lane * 2) = o;
}

extern "C" void kernel_launch(void* const* d_in, const int* in_sizes, int n_in,
                              void* d_out, int out_size, void* d_ws, size_t ws_size,
                              hipStream_t stream) {
    const float* x    = (const float*)d_in[0];
    const float* W    = (const float*)d_in[1];
    const int*   rows = (const int*)d_in[2];
    const int*   cols = (const int*)d_in[3];
    const float* vals = (const float*)d_in[4];
    float* out = (float*)d_out;

    char* ws = (char*)d_ws;
    size_t off = 0;
    unsigned short* hb  = (unsigned short*)(ws + off); off += ((size_t)N_NODES * D_OUT * 2 + 255) & ~(size_t)255;
    unsigned short* WbT = (unsigned short*)(ws + off); off += ((size_t)D_IN * D_OUT * 2 + 255) & ~(size_t)255;
    int*  cursor = (int*)(ws + off); off += ((size_t)N_NODES * 4 + 255) & ~(size_t)255;

    const size_t bucket_bytes = (size_t)N_NODES * CAP * 8;   // 51.2 MB (int2 entries)

    if (ws_size >= off + bucket_bytes) {
        // ---- PRIMARY: 3 dispatches (convert -> fused gemm+scatter -> gather) ----
        int2* buckets = (int2*)(ws + off);
        convert_w<<<(D_IN * D_OUT) / 256, 256, 0, stream>>>(W, WbT, cursor, 1);
        gemm_scatter<<<GEMM_BLOCKS + NWIN * PERM_SLICES, 256, 0, stream>>>(
            x, WbT, hb, rows, cols, vals, cursor, buckets);
        gather_bucket<<<(N_NODES + 3) / 4, 256, 0, stream>>>(cursor, buckets, hb, out);
    } else {
        // ---- FALLBACK: hist + scan + permute (round-7 pipeline) ----
        int*  ptr    = (int*)(ws + off); size_t off2 = off + (((size_t)(N_NODES + 1) * 4 + 255) & ~(size_t)255);
        int2* edge_r = (int2*)(ws + off2); off2 += ((size_t)N_EDGES * 8 + 255) & ~(size_t)255;
        int*  bsum   = (int*)(ws + off2);

        convert_w<<<(D_IN * D_OUT) / 256, 256, 0, stream>>>(W, WbT, cursor, 0);
        gemm_mfma<<<GEMM_BLOCKS, 256, 0, stream>>>(x, WbT, hb);
        hist_rows<<<(N_EDGES / 4 + 255) / 256, 256, 0, stream>>>(rows, cursor);
        scan_reduce<<<NSCAN, 1024, 0, stream>>>(cursor, bsum, N_NODES);
        scan_apply<<<NSCAN, 1024, 0, stream>>>(cursor, bsum, ptr, cursor, N_NODES, NSCAN);
        permute_edges<<<NWIN * PERM_SLICES, 256, 0, stream>>>(rows, cols, vals, cursor, edge_r);
        gather_rows<<<(N_NODES + 3) / 4, 256, 0, stream>>>(ptr, edge_r, hb, out);
    }
}

// Round 12
// 373.227 us; speedup vs baseline: 1.0971x; 1.0046x over previous
//
#include <hip/hip_runtime.h>
#include <hip/hip_bf16.h>

#define N_NODES 100000
#define N_EDGES 1600000
#define D_IN 256
#define D_OUT 128
#define CAP 64            /* padded bucket capacity per row (max degree ~40) */

typedef short bf16x8 __attribute__((ext_vector_type(8)));
typedef float f32x4 __attribute__((ext_vector_type(4)));
typedef float f32x2 __attribute__((ext_vector_type(2)));

__device__ __forceinline__ unsigned short f2bf(float f) {
    unsigned int u = __builtin_bit_cast(unsigned int, f);
    u += 0x7fffu + ((u >> 16) & 1u);   // round-to-nearest-even
    return (unsigned short)(u >> 16);
}
__device__ __forceinline__ float bf_lo(unsigned int h) {
    return __builtin_bit_cast(float, h << 16);
}
__device__ __forceinline__ float bf_hi(unsigned int h) {
    return __builtin_bit_cast(float, h & 0xffff0000u);
}

// ---------- W transpose+convert + cursor init ----------
__global__ __launch_bounds__(256) void convert_w(const float* __restrict__ W,
                                                 unsigned short* __restrict__ WbT,
                                                 int* __restrict__ cursor,
                                                 int bucket_mode) {
    int i = blockIdx.x * 256 + threadIdx.x;      // 32768 total
    int k = i >> 7;
    int n = i & 127;
    WbT[(size_t)n * D_IN + k] = f2bf(W[i]);
    int z = i * 4;                                // init 100000 ints (int4 stores)
    if (z < N_NODES) {
        int4 v = bucket_mode ? make_int4(z << 6, (z << 6) + CAP, (z << 6) + 2 * CAP, (z << 6) + 3 * CAP)
                             : make_int4(0, 0, 0, 0);
        *(int4*)(cursor + z) = v;
    }
}

// ---------- FUSED gemm + scatter, INTERLEAVED block assignment ----------
// r11 lesson: grid-partitioned halves run sequentially (blocks dispatch in
// order; grid > resident capacity) -> fusion saved only the launch gap.
// Fix: period-7 interleave (2 gemm + 5 scatter per 7 blocks) so every CU
// co-hosts gemm waves (latency-bound, idle atomic slots) and scatter waves
// (atomic-bound, idle load slots). gemm half reverted to the 32-rows/wave
// structure (r3: standalone <78us; B-fragment shared by 2 A-frags).
#define GEMM_UNITS 782                  /* ceil(100000/128) blocks of 128 rows */
#define NWIN 8
#define ROWS_PER_WIN (N_NODES / NWIN)   /* 12500 */
#define PERM_SLICES 250                 /* 2000 scatter units */
#define FUSED_GRID 2800                 /* 400 periods x 7 */
__global__ __launch_bounds__(256) void gemm_scatter(const float* __restrict__ x,
                                                    const unsigned short* __restrict__ WbT,
                                                    unsigned short* __restrict__ hb,
                                                    const int* __restrict__ rows,
                                                    const int* __restrict__ cols,
                                                    const float* __restrict__ vals,
                                                    int* __restrict__ cursor,
                                                    int2* __restrict__ buckets) {
    const int b = blockIdx.x;
    const int phase = b % 7;
    if (phase >= 2) {
        // ---- scatter unit: single-pass 8-window (r8-proven) ----
        const int s = (b / 7) * 5 + (phase - 2);      // 0..1999
        if (s >= NWIN * PERM_SLICES) return;
        const int w     = s & (NWIN - 1);
        const int slice = s >> 3;                     // 0..249
        const int lo = w * ROWS_PER_WIN;
        const int hi = lo + ROWS_PER_WIN;
        const int per = (N_EDGES / 4) / PERM_SLICES;  // 1600
        const int beg = slice * per;
        const int end = beg + per;
        for (int i = beg + (int)threadIdx.x; i < end; i += 256) {
            int4 r = *((const int4*)rows + i);
            const int e = i * 4;
            if (r.x >= lo && r.x < hi) {
                int p = atomicAdd(&cursor[r.x], 1);
                buckets[p] = make_int2(cols[e + 0], __builtin_bit_cast(int, vals[e + 0]));
            }
            if (r.y >= lo && r.y < hi) {
                int p = atomicAdd(&cursor[r.y], 1);
                buckets[p] = make_int2(cols[e + 1], __builtin_bit_cast(int, vals[e + 1]));
            }
            if (r.z >= lo && r.z < hi) {
                int p = atomicAdd(&cursor[r.z], 1);
                buckets[p] = make_int2(cols[e + 2], __builtin_bit_cast(int, vals[e + 2]));
            }
            if (r.w >= lo && r.w < hi) {
                int p = atomicAdd(&cursor[r.w], 1);
                buckets[p] = make_int2(cols[e + 3], __builtin_bit_cast(int, vals[e + 3]));
            }
        }
        return;
    }

    // ---- gemm unit: 128 rows/block, 32 rows/wave, MFMA 16x16x32 ----
    const int g = (b / 7) * 2 + phase;                // 0..799
    if (g >= GEMM_UNITS) return;
    const int wave = threadIdx.x >> 6;
    const int lane = threadIdx.x & 63;
    const int row0 = g * 128 + wave * 32;
    if (row0 >= N_NODES) return;                 // wave-uniform (100000 % 32 == 0)
    const int m = lane & 15;
    const int q = lane >> 4;

    const float* xr0 = x + (size_t)(row0 + m) * D_IN;
    const float* xr1 = x + (size_t)(row0 + 16 + m) * D_IN;

    f32x4 acc[2][8];
#pragma unroll
    for (int h = 0; h < 2; ++h)
#pragma unroll
        for (int nt = 0; nt < 8; ++nt) acc[h][nt] = (f32x4){0.f, 0.f, 0.f, 0.f};

#pragma unroll
    for (int kc = 0; kc < 8; ++kc) {
        const int kb = kc * 32 + q * 8;
        float4 a00 = *(const float4*)(xr0 + kb);
        float4 a01 = *(const float4*)(xr0 + kb + 4);
        float4 a10 = *(const float4*)(xr1 + kb);
        float4 a11 = *(const float4*)(xr1 + kb + 4);
        bf16x8 af0, af1;
        af0[0] = (short)f2bf(a00.x); af0[1] = (short)f2bf(a00.y);
        af0[2] = (short)f2bf(a00.z); af0[3] = (short)f2bf(a00.w);
        af0[4] = (short)f2bf(a01.x); af0[5] = (short)f2bf(a01.y);
        af0[6] = (short)f2bf(a01.z); af0[7] = (short)f2bf(a01.w);
        af1[0] = (short)f2bf(a10.x); af1[1] = (short)f2bf(a10.y);
        af1[2] = (short)f2bf(a10.z); af1[3] = (short)f2bf(a10.w);
        af1[4] = (short)f2bf(a11.x); af1[5] = (short)f2bf(a11.y);
        af1[6] = (short)f2bf(a11.z); af1[7] = (short)f2bf(a11.w);
#pragma unroll
        for (int nt = 0; nt < 8; ++nt) {
            bf16x8 bf = *(const bf16x8*)(WbT + (size_t)(nt * 16 + m) * D_IN + kb);
            acc[0][nt] = __builtin_amdgcn_mfma_f32_16x16x32_bf16(af0, bf, acc[0][nt], 0, 0, 0);
            acc[1][nt] = __builtin_amdgcn_mfma_f32_16x16x32_bf16(af1, bf, acc[1][nt], 0, 0, 0);
        }
    }

    // D layout: row = q*4 + r, col = nt*16 + m
#pragma unroll
    for (int h = 0; h < 2; ++h)
#pragma unroll
        for (int nt = 0; nt < 8; ++nt)
#pragma unroll
            for (int r = 0; r < 4; ++r) {
                int grow = row0 + h * 16 + q * 4 + r;
                hb[(size_t)grow * D_OUT + nt * 16 + m] = f2bf(acc[h][nt][r]);
            }
}

// ---------- gather: 8-deep edge ILP; beg = row*CAP, end = cursor[row] ----------
__global__ __launch_bounds__(256) void gather_bucket(const int* __restrict__ cursor,
                                                     const int2* __restrict__ buckets,
                                                     const unsigned short* __restrict__ hb,
                                                     float* __restrict__ out) {
    int row  = blockIdx.x * 4 + (threadIdx.x >> 6);
    int lane = threadIdx.x & 63;
    if (row >= N_NODES) return;
    int beg = row << 6;                                            // row*CAP
    int end = __builtin_amdgcn_readfirstlane(cursor[row]);

    float ax0 = 0.f, ay0 = 0.f, ax1 = 0.f, ay1 = 0.f;
    float ax2 = 0.f, ay2 = 0.f, ax3 = 0.f, ay3 = 0.f;
    float ax4 = 0.f, ay4 = 0.f, ax5 = 0.f, ay5 = 0.f;
    float ax6 = 0.f, ay6 = 0.f, ax7 = 0.f, ay7 = 0.f;
    int j = beg;
    for (; j + 8 <= end; j += 8) {
        int4 p01 = *(const int4*)(buckets + j);
        int4 p23 = *(const int4*)(buckets + j + 2);
        int4 p45 = *(const int4*)(buckets + j + 4);
        int4 p67 = *(const int4*)(buckets + j + 6);
        unsigned int h0 = *(const unsigned int*)(hb + (size_t)p01.x * D_OUT + lane * 2);
        unsigned int h1 = *(const unsigned int*)(hb + (size_t)p01.z * D_OUT + lane * 2);
        unsigned int h2 = *(const unsigned int*)(hb + (size_t)p23.x * D_OUT + lane * 2);
        unsigned int h3 = *(const unsigned int*)(hb + (size_t)p23.z * D_OUT + lane * 2);
        unsigned int h4 = *(const unsigned int*)(hb + (size_t)p45.x * D_OUT + lane * 2);
        unsigned int h5 = *(const unsigned int*)(hb + (size_t)p45.z * D_OUT + lane * 2);
        unsigned int h6 = *(const unsigned int*)(hb + (size_t)p67.x * D_OUT + lane * 2);
        unsigned int h7 = *(const unsigned int*)(hb + (size_t)p67.z * D_OUT + lane * 2);
        float v0 = __builtin_bit_cast(float, p01.y);
        float v1 = __builtin_bit_cast(float, p01.w);
        float v2 = __builtin_bit_cast(float, p23.y);
        float v3 = __builtin_bit_cast(float, p23.w);
        float v4 = __builtin_bit_cast(float, p45.y);
        float v5 = __builtin_bit_cast(float, p45.w);
        float v6 = __builtin_bit_cast(float, p67.y);
        float v7 = __builtin_bit_cast(float, p67.w);
        ax0 = fmaf(v0, bf_lo(h0), ax0); ay0 = fmaf(v0, bf_hi(h0), ay0);
        ax1 = fmaf(v1, bf_lo(h1), ax1); ay1 = fmaf(v1, bf_hi(h1), ay1);
        ax2 = fmaf(v2, bf_lo(h2), ax2); ay2 = fmaf(v2, bf_hi(h2), ay2);
        ax3 = fmaf(v3, bf_lo(h3), ax3); ay3 = fmaf(v3, bf_hi(h3), ay3);
        ax4 = fmaf(v4, bf_lo(h4), ax4); ay4 = fmaf(v4, bf_hi(h4), ay4);
        ax5 = fmaf(v5, bf_lo(h5), ax5); ay5 = fmaf(v5, bf_hi(h5), ay5);
        ax6 = fmaf(v6, bf_lo(h6), ax6); ay6 = fmaf(v6, bf_hi(h6), ay6);
        ax7 = fmaf(v7, bf_lo(h7), ax7); ay7 = fmaf(v7, bf_hi(h7), ay7);
    }
    for (; j + 4 <= end; j += 4) {
        int4 p01 = *(const int4*)(buckets + j);
        int4 p23 = *(const int4*)(buckets + j + 2);
        unsigned int h0 = *(const unsigned int*)(hb + (size_t)p01.x * D_OUT + lane * 2);
        unsigned int h1 = *(const unsigned int*)(hb + (size_t)p01.z * D_OUT + lane * 2);
        unsigned int h2 = *(const unsigned int*)(hb + (size_t)p23.x * D_OUT + lane * 2);
        unsigned int h3 = *(const unsigned int*)(hb + (size_t)p23.z * D_OUT + lane * 2);
        float v0 = __builtin_bit_cast(float, p01.y);
        float v1 = __builtin_bit_cast(float, p01.w);
        float v2 = __builtin_bit_cast(float, p23.y);
        float v3 = __builtin_bit_cast(float, p23.w);
        ax0 = fmaf(v0, bf_lo(h0), ax0); ay0 = fmaf(v0, bf_hi(h0), ay0);
        ax1 = fmaf(v1, bf_lo(h1), ax1); ay1 = fmaf(v1, bf_hi(h1), ay1);
        ax2 = fmaf(v2, bf_lo(h2), ax2); ay2 = fmaf(v2, bf_hi(h2), ay2);
        ax3 = fmaf(v3, bf_lo(h3), ax3); ay3 = fmaf(v3, bf_hi(h3), ay3);
    }
    for (; j < end; ++j) {
        int2 e = buckets[j];
        unsigned int h = *(const unsigned int*)(hb + (size_t)e.x * D_OUT + lane * 2);
        float v = __builtin_bit_cast(float, e.y);
        ax0 = fmaf(v, bf_lo(h), ax0);
        ay0 = fmaf(v, bf_hi(h), ay0);
    }
    float accx = ((ax0 + ax1) + (ax2 + ax3)) + ((ax4 + ax5) + (ax6 + ax7));
    float accy = ((ay0 + ay1) + (ay2 + ay3)) + ((ay4 + ay5) + (ay6 + ay7));
    f32x2 o;
    o[0] = fmaxf(accx, 0.f);
    o[1] = fmaxf(accy, 0.f);
    __builtin_nontemporal_store(o, (f32x2*)(out + (size_t)row * D_OUT + lane * 2));
}

// ================== FALLBACK path (small workspace): round-7 pipeline ==================
__global__ __launch_bounds__(256) void gemm_mfma(const float* __restrict__ x,
                                                 const unsigned short* __restrict__ WbT,
                                                 unsigned short* __restrict__ hb) {
    const int wave = threadIdx.x >> 6;
    const int lane = threadIdx.x & 63;
    const int row0 = blockIdx.x * 64 + wave * 16;
    if (row0 >= N_NODES) return;
    const int m = lane & 15;
    const int q = lane >> 4;

    const float* xr = x + (size_t)(row0 + m) * D_IN + q * 8;

    float4 a[8][2];
#pragma unroll
    for (int kc = 0; kc < 8; ++kc) {
        a[kc][0] = *(const float4*)(xr + kc * 32);
        a[kc][1] = *(const float4*)(xr + kc * 32 + 4);
    }

    bf16x8 af[8];
#pragma unroll
    for (int kc = 0; kc < 8; ++kc) {
        af[kc][0] = (short)f2bf(a[kc][0].x); af[kc][1] = (short)f2bf(a[kc][0].y);
        af[kc][2] = (short)f2bf(a[kc][0].z); af[kc][3] = (short)f2bf(a[kc][0].w);
        af[kc][4] = (short)f2bf(a[kc][1].x); af[kc][5] = (short)f2bf(a[kc][1].y);
        af[kc][6] = (short)f2bf(a[kc][1].z); af[kc][7] = (short)f2bf(a[kc][1].w);
    }

    f32x4 acc[8];
#pragma unroll
    for (int nt = 0; nt < 8; ++nt) acc[nt] = (f32x4){0.f, 0.f, 0.f, 0.f};

#pragma unroll
    for (int kc = 0; kc < 8; ++kc) {
        const int kb = kc * 32 + q * 8;
#pragma unroll
        for (int nt = 0; nt < 8; ++nt) {
            bf16x8 bf = *(const bf16x8*)(WbT + (size_t)(nt * 16 + m) * D_IN + kb);
            acc[nt] = __builtin_amdgcn_mfma_f32_16x16x32_bf16(af[kc], bf, acc[nt], 0, 0, 0);
        }
    }

#pragma unroll
    for (int nt = 0; nt < 8; ++nt)
#pragma unroll
        for (int r = 0; r < 4; ++r) {
            int grow = row0 + q * 4 + r;
            hb[(size_t)grow * D_OUT + nt * 16 + m] = f2bf(acc[nt][r]);
        }
}

__global__ __launch_bounds__(256) void hist_rows(const int* __restrict__ rows,
                                                 int* __restrict__ counts) {
    int i = blockIdx.x * 256 + threadIdx.x;
    if (i < N_EDGES / 4) {
        int4 r = *(const int4*)(rows + i * 4);
        atomicAdd(&counts[r.x], 1);
        atomicAdd(&counts[r.y], 1);
        atomicAdd(&counts[r.z], 1);
        atomicAdd(&counts[r.w], 1);
    }
}

#define SCHUNK 1024
#define NSCAN ((N_NODES + SCHUNK - 1) / SCHUNK)   /* 98 */
__global__ __launch_bounds__(1024) void scan_reduce(const int* __restrict__ counts,
                                                    int* __restrict__ bsum, int n) {
    __shared__ int ws[16];
    const int t = threadIdx.x, lane = t & 63, wid = t >> 6;
    int i = blockIdx.x * SCHUNK + t;
    int v = (i < n) ? counts[i] : 0;
#pragma unroll
    for (int off = 32; off >= 1; off >>= 1) v += __shfl_down(v, off);
    if (lane == 0) ws[wid] = v;
    __syncthreads();
    if (t == 0) {
        int s = 0;
#pragma unroll
        for (int w = 0; w < 16; ++w) s += ws[w];
        bsum[blockIdx.x] = s;
    }
}

__global__ __launch_bounds__(1024) void scan_apply(const int* __restrict__ counts,
                                                   const int* __restrict__ bsum,
                                                   int* __restrict__ ptr,
                                                   int* __restrict__ cursor, int n, int nb) {
    __shared__ int wtot[16];
    __shared__ int bpre[128];
    const int t = threadIdx.x, lane = t & 63, wid = t >> 6;
    int i = blockIdx.x * SCHUNK + t;
    int v = (i < n) ? counts[i] : 0;
    int x = v;
#pragma unroll
    for (int off = 1; off < 64; off <<= 1) {
        int u = __shfl_up(x, off);
        if (lane >= off) x += u;
    }
    if (lane == 63) wtot[wid] = x;

    if (wid == 0) {
        int carry = 0;
        for (int base = 0; base < nb; base += 64) {
            int idx = base + lane;
            int bv = (idx < nb) ? bsum[idx] : 0;
            int bx = bv;
#pragma unroll
            for (int off = 1; off < 64; off <<= 1) {
                int u = __shfl_up(bx, off);
                if (lane >= off) bx += u;
            }
            if (idx < nb) bpre[idx] = bx - bv + carry;
            carry += __shfl(bx, 63);
        }
    }
    __syncthreads();
    if (wid == 0) {
        int wv = (lane < 16) ? wtot[lane] : 0;
        int y = wv;
#pragma unroll
        for (int off = 1; off < 16; off <<= 1) {
            int u = __shfl_up(y, off);
            if (lane >= off) y += u;
        }
        if (lane < 16) wtot[lane] = y - wv;
    }
    __syncthreads();
    int excl = (x - v) + wtot[wid] + bpre[blockIdx.x];
    if (i < n) {
        ptr[i] = excl;
        cursor[i] = excl;
        if (i == n - 1) ptr[n] = excl + v;
    }
}

__global__ __launch_bounds__(256) void permute_edges(const int* __restrict__ rows,
                                                     const int* __restrict__ cols,
                                                     const float* __restrict__ vals,
                                                     int* __restrict__ cursor,
                                                     int2* __restrict__ edge_r) {
    const int w     = blockIdx.x & 7;
    const int slice = blockIdx.x >> 3;
    const int lo = w * (N_NODES / 8);
    const int hi = lo + (N_NODES / 8);
    const int per = (N_EDGES / 4) / PERM_SLICES;
    const int beg = slice * per;
    const int end = beg + per;
    for (int i = beg + (int)threadIdx.x; i < end; i += 256) {
        int4 r = *((const int4*)rows + i);
        const int e = i * 4;
        if (r.x >= lo && r.x < hi) {
            int p = atomicAdd(&cursor[r.x], 1);
            edge_r[p] = make_int2(cols[e + 0], __builtin_bit_cast(int, vals[e + 0]));
        }
        if (r.y >= lo && r.y < hi) {
            int p = atomicAdd(&cursor[r.y], 1);
            edge_r[p] = make_int2(cols[e + 1], __builtin_bit_cast(int, vals[e + 1]));
        }
        if (r.z >= lo && r.z < hi) {
            int p = atomicAdd(&cursor[r.z], 1);
            edge_r[p] = make_int2(cols[e + 2], __builtin_bit_cast(int, vals[e + 2]));
        }
        if (r.w >= lo && r.w < hi) {
            int p = atomicAdd(&cursor[r.w], 1);
            edge_r[p] = make_int2(cols[e + 3], __builtin_bit_cast(int, vals[e + 3]));
        }
    }
}

__global__ __launch_bounds__(256) void gather_rows(const int* __restrict__ ptr,
                                                   const int2* __restrict__ edge_r,
                                                   const unsigned short* __restrict__ hb,
                                                   float* __restrict__ out) {
    int row  = blockIdx.x * 4 + (threadIdx.x >> 6);
    int lane = threadIdx.x & 63;
    if (row >= N_NODES) return;
    int beg = __builtin_amdgcn_readfirstlane(ptr[row]);
    int end = __builtin_amdgcn_readfirstlane(ptr[row + 1]);

    float ax0 = 0.f, ay0 = 0.f, ax1 = 0.f, ay1 = 0.f;
    float ax2 = 0.f, ay2 = 0.f, ax3 = 0.f, ay3 = 0.f;
    int j = beg;
    for (; j + 4 <= end; j += 4) {
        int2 e0 = edge_r[j + 0];
        int2 e1 = edge_r[j + 1];
        int2 e2 = edge_r[j + 2];
        int2 e3 = edge_r[j + 3];
        unsigned int h0 = *(const unsigned int*)(hb + (size_t)e0.x * D_OUT + lane * 2);
        unsigned int h1 = *(const unsigned int*)(hb + (size_t)e1.x * D_OUT + lane * 2);
        unsigned int h2 = *(const unsigned int*)(hb + (size_t)e2.x * D_OUT + lane * 2);
        unsigned int h3 = *(const unsigned int*)(hb + (size_t)e3.x * D_OUT + lane * 2);
        float v0 = __builtin_bit_cast(float, e0.y);
        float v1 = __builtin_bit_cast(float, e1.y);
        float v2 = __builtin_bit_cast(float, e2.y);
        float v3 = __builtin_bit_cast(float, e3.y);
        ax0 = fmaf(v0, bf_lo(h0), ax0); ay0 = fmaf(v0, bf_hi(h0), ay0);
        ax1 = fmaf(v1, bf_lo(h1), ax1); ay1 = fmaf(v1, bf_hi(h1), ay1);
        ax2 = fmaf(v2, bf_lo(h2), ax2); ay2 = fmaf(v2, bf_hi(h2), ay2);
        ax3 = fmaf(v3, bf_lo(h3), ax3); ay3 = fmaf(v3, bf_hi(h3), ay3);
    }
    for (; j < end; ++j) {
        int2 e = edge_r[j];
        unsigned int h = *(const unsigned int*)(hb + (size_t)e.x * D_OUT + lane * 2);
        float v = __builtin_bit_cast(float, e.y);
        ax0 = fmaf(v, bf_lo(h), ax0);
        ay0 = fmaf(v, bf_hi(h), ay0);
    }
    float accx = (ax0 + ax1) + (ax2 + ax3);
    float accy = (ay0 + ay1) + (ay2 + ay3);
    float2 o = make_float2(fmaxf(accx, 0.f), fmaxf(accy, 0.f));
    *(float2*)(out + (size_t)row * D_OUT + lane * 2) = o;
}

extern "C" void kernel_launch(void* const* d_in, const int* in_sizes, int n_in,
                              void* d_out, int out_size, void* d_ws, size_t ws_size,
                              hipStream_t stream) {
    const float* x    = (const float*)d_in[0];
    const float* W    = (const float*)d_in[1];
    const int*   rows = (const int*)d_in[2];
    const int*   cols = (const int*)d_in[3];
    const float* vals = (const float*)d_in[4];
    float* out = (float*)d_out;

    char* ws = (char*)d_ws;
    size_t off = 0;
    unsigned short* hb  = (unsigned short*)(ws + off); off += ((size_t)N_NODES * D_OUT * 2 + 255) & ~(size_t)255;
    unsigned short* WbT = (unsigned short*)(ws + off); off += ((size_t)D_IN * D_OUT * 2 + 255) & ~(size_t)255;
    int*  cursor = (int*)(ws + off); off += ((size_t)N_NODES * 4 + 255) & ~(size_t)255;

    const size_t bucket_bytes = (size_t)N_NODES * CAP * 8;   // 51.2 MB (int2 entries)

    if (ws_size >= off + bucket_bytes) {
        // ---- PRIMARY: 3 dispatches (convert -> interleaved gemm+scatter -> gather) ----
        int2* buckets = (int2*)(ws + off);
        convert_w<<<(D_IN * D_OUT) / 256, 256, 0, stream>>>(W, WbT, cursor, 1);
        gemm_scatter<<<FUSED_GRID, 256, 0, stream>>>(
            x, WbT, hb, rows, cols, vals, cursor, buckets);
        gather_bucket<<<(N_NODES + 3) / 4, 256, 0, stream>>>(cursor, buckets, hb, out);
    } else {
        // ---- FALLBACK: hist + scan + permute (round-7 pipeline) ----
        int*  ptr    = (int*)(ws + off); size_t off2 = off + (((size_t)(N_NODES + 1) * 4 + 255) & ~(size_t)255);
        int2* edge_r = (int2*)(ws + off2); off2 += ((size_t)N_EDGES * 8 + 255) & ~(size_t)255;
        int*  bsum   = (int*)(ws + off2);

        convert_w<<<(D_IN * D_OUT) / 256, 256, 0, stream>>>(W, WbT, cursor, 0);
        gemm_mfma<<<(N_NODES + 63) / 64, 256, 0, stream>>>(x, WbT, hb);
        hist_rows<<<(N_EDGES / 4 + 255) / 256, 256, 0, stream>>>(rows, cursor);
        scan_reduce<<<NSCAN, 1024, 0, stream>>>(cursor, bsum, N_NODES);
        scan_apply<<<NSCAN, 1024, 0, stream>>>(cursor, bsum, ptr, cursor, N_NODES, NSCAN);
        permute_edges<<<NWIN * PERM_SLICES, 256, 0, stream>>>(rows, cols, vals, cursor, edge_r);
        gather_rows<<<(N_NODES + 3) / 4, 256, 0, stream>>>(ptr, edge_r, hb, out);
    }
}